// Round 1
// baseline (166.819 us; speedup 1.0000x reference)
//
#include <hip/hip_runtime.h>
#include <stdint.h>
#include <stddef.h>

#define NCELLS (512 * 512)   // 262144 grid cells
#define CG 64                // grid embedding channels
#define CPC 64               // point-cloud channels
#define CIN 128              // concat width
#define CH 32                // hidden width
#define COUT 3

// ---------------------------------------------------------------------------
// prep: transpose Y_w (32x128 row-major) -> YwT (128x32, c-major) so that the
// per-k-chunk weight slices are contiguous (friendly for s_load_dwordx16).
// Also detect grid_indices element width: reference says int64, but if the
// harness's JAX ran without x64 it is int32. If the buffer is int64, every
// 8-byte read is < 2^18 (indices < 262144 => high word 0). If it is int32,
// an 8-byte read combines two indices and is >= 2^32 unless the odd-position
// index happens to be 0 (prob (1/262144)^8 over 8 probes ~ 0).
// ---------------------------------------------------------------------------
__global__ void prep_kernel(const float* __restrict__ Yw,
                            const unsigned long long* __restrict__ idx_as_u64,
                            float* __restrict__ YwT,
                            int* __restrict__ flag_is64) {
    int t = threadIdx.x;
    for (int k = t; k < CIN * CH; k += 256) {
        int c = k >> 5;      // 0..127
        int j = k & 31;      // 0..31
        YwT[k] = Yw[j * CIN + c];
    }
    if (t == 0) {
        int is64 = 1;
        for (int i = 0; i < 8; ++i) {
            if (idx_as_u64[i] >= (unsigned long long)NCELLS) { is64 = 0; break; }
        }
        *flag_is64 = is64;
    }
}

// ---------------------------------------------------------------------------
// Precompute G[p][j] = Y_b[j] + sum_c grid[c][p] * Y_w[j][c]   (c < 64)
// grid is (64, 262144) channel-major: reads are perfectly coalesced along p.
// G is (262144, 32) row-major: 128B contiguous per cell.
// ---------------------------------------------------------------------------
__global__ void __launch_bounds__(256)
precompute_G(const float* __restrict__ grid,
             const float* __restrict__ YwT,   // (128,32) c-major
             const float* __restrict__ Yb,    // (32,)
             float* __restrict__ G) {
    int p = blockIdx.x * blockDim.x + threadIdx.x;
    if (p >= NCELLS) return;

    float acc[CH];
#pragma unroll
    for (int j = 0; j < CH; ++j) acc[j] = Yb[j];

#pragma unroll 4
    for (int c = 0; c < CG; ++c) {
        float g = grid[(size_t)c * NCELLS + p];
        const float* w = YwT + c * CH;   // wave-uniform address -> scalar loads
#pragma unroll
        for (int j = 0; j < CH; ++j) acc[j] = fmaf(w[j], g, acc[j]);
    }

    float4* Gp = (float4*)(G + (size_t)p * CH);
#pragma unroll
    for (int q = 0; q < CH / 4; ++q)
        Gp[q] = make_float4(acc[4 * q], acc[4 * q + 1], acc[4 * q + 2], acc[4 * q + 3]);
}

// ---------------------------------------------------------------------------
// Main: one thread per point.
//   h = G[idx] + Y_w[:,64:] @ pc[i]   (2048 FMAs, weights via scalar loads)
//   out = Z_w @ h + Z_b               (96 FMAs)
// ---------------------------------------------------------------------------
__global__ void __launch_bounds__(256)
main_kernel(const float* __restrict__ G,
            const float* __restrict__ pc,       // (N,64)
            const void* __restrict__ idx_raw,
            const float* __restrict__ YwT,      // (128,32) c-major
            const float* __restrict__ Zw,       // (3,32)
            const float* __restrict__ Zb,       // (3,)
            const int* __restrict__ flag_is64,
            float* __restrict__ out, int N) {
    int i = blockIdx.x * blockDim.x + threadIdx.x;
    if (i >= N) return;

    int is64 = *flag_is64;   // uniform branch
    int idx;
    if (is64) idx = (int)(((const long long*)idx_raw)[i]);
    else      idx = ((const int*)idx_raw)[i];

    float h[CH];
    const float4* Gp = (const float4*)(G + (size_t)idx * CH);
#pragma unroll
    for (int q = 0; q < CH / 4; ++q) {
        float4 v = Gp[q];
        h[4 * q + 0] = v.x; h[4 * q + 1] = v.y;
        h[4 * q + 2] = v.z; h[4 * q + 3] = v.w;
    }

    const float4* pcp = (const float4*)(pc + (size_t)i * CPC);
#pragma unroll 2
    for (int c4 = 0; c4 < CPC / 4; ++c4) {
        float4 x = pcp[c4];
        const float* w = YwT + (CG + c4 * 4) * CH;   // 128 contiguous scalars
#pragma unroll
        for (int j = 0; j < CH; ++j) {
            h[j] = fmaf(w[0 * CH + j], x.x, h[j]);
            h[j] = fmaf(w[1 * CH + j], x.y, h[j]);
            h[j] = fmaf(w[2 * CH + j], x.z, h[j]);
            h[j] = fmaf(w[3 * CH + j], x.w, h[j]);
        }
    }

#pragma unroll
    for (int t = 0; t < COUT; ++t) {
        float a = Zb[t];
#pragma unroll
        for (int j = 0; j < CH; ++j) a = fmaf(Zw[t * CH + j], h[j], a);
        out[(size_t)i * COUT + t] = a;
    }
}

// ---------------------------------------------------------------------------
// Fallback (only if ws_size is too small for the G table): direct strided
// gather from grid + full 128-wide dot. Slow but correct.
// ---------------------------------------------------------------------------
__global__ void __launch_bounds__(256)
direct_kernel(const float* __restrict__ grid,
              const float* __restrict__ pc,
              const void* __restrict__ idx_raw,
              const float* __restrict__ Yw,   // (32,128) row-major
              const float* __restrict__ Yb,
              const float* __restrict__ Zw,
              const float* __restrict__ Zb,
              const int* __restrict__ flag_is64,  // may be null
              int is64_default,
              float* __restrict__ out, int N) {
    int i = blockIdx.x * blockDim.x + threadIdx.x;
    if (i >= N) return;

    int is64 = flag_is64 ? *flag_is64 : is64_default;
    int idx;
    if (is64) idx = (int)(((const long long*)idx_raw)[i]);
    else      idx = ((const int*)idx_raw)[i];

    float h[CH];
#pragma unroll
    for (int j = 0; j < CH; ++j) h[j] = Yb[j];

    for (int c = 0; c < CG; ++c) {
        float g = grid[(size_t)c * NCELLS + idx];
#pragma unroll
        for (int j = 0; j < CH; ++j) h[j] = fmaf(Yw[j * CIN + c], g, h[j]);
    }

    const float4* pcp = (const float4*)(pc + (size_t)i * CPC);
#pragma unroll 2
    for (int c4 = 0; c4 < CPC / 4; ++c4) {
        float4 x = pcp[c4];
#pragma unroll
        for (int j = 0; j < CH; ++j) {
            const float* w = Yw + j * CIN + CG + c4 * 4;
            h[j] = fmaf(w[0], x.x, h[j]);
            h[j] = fmaf(w[1], x.y, h[j]);
            h[j] = fmaf(w[2], x.z, h[j]);
            h[j] = fmaf(w[3], x.w, h[j]);
        }
    }

#pragma unroll
    for (int t = 0; t < COUT; ++t) {
        float a = Zb[t];
#pragma unroll
        for (int j = 0; j < CH; ++j) a = fmaf(Zw[t * CH + j], h[j], a);
        out[(size_t)i * COUT + t] = a;
    }
}

extern "C" void kernel_launch(void* const* d_in, const int* in_sizes, int n_in,
                              void* d_out, int out_size, void* d_ws, size_t ws_size,
                              hipStream_t stream) {
    const float* grid = (const float*)d_in[0];   // (64,512,512)
    const float* pc   = (const float*)d_in[1];   // (N,64)
    const void*  idx  = d_in[2];                 // (N,) int64 (or int32, detected)
    const float* Yw   = (const float*)d_in[3];   // (32,128)
    const float* Yb   = (const float*)d_in[4];   // (32,)
    const float* Zw   = (const float*)d_in[5];   // (3,32)
    const float* Zb   = (const float*)d_in[6];   // (3,)
    float* out = (float*)d_out;
    const int N = in_sizes[2];

    const size_t G_bytes   = (size_t)NCELLS * CH * sizeof(float);  // 32 MiB
    const size_t YwT_bytes = (size_t)CIN * CH * sizeof(float);     // 16 KiB
    const size_t need      = G_bytes + YwT_bytes + sizeof(int);

    const int threads = 256;
    const int main_blocks = (N + threads - 1) / threads;

    if (ws_size >= need) {
        float* G    = (float*)d_ws;
        float* YwT  = (float*)((char*)d_ws + G_bytes);
        int*   flag = (int*)((char*)d_ws + G_bytes + YwT_bytes);

        prep_kernel<<<1, 256, 0, stream>>>(Yw, (const unsigned long long*)idx, YwT, flag);
        precompute_G<<<NCELLS / threads, threads, 0, stream>>>(grid, YwT, Yb, G);
        main_kernel<<<main_blocks, threads, 0, stream>>>(G, pc, idx, YwT, Zw, Zb, flag, out, N);
    } else if (ws_size >= 64 * sizeof(float) + 8 * CH * sizeof(float)) {
        // enough for a flag at least; use direct path with on-device detection
        int* flag = (int*)d_ws;
        float* YwT_dummy = (float*)((char*)d_ws + 64);  // prep needs a YwT target; reuse ws scratch
        // prep also transposes (harmless; 16KB doesn't fit here, so skip transpose via direct kernel)
        // just do detection with a 1-thread kernel reusing prep's logic:
        prep_kernel<<<1, 1, 0, stream>>>(Yw, (const unsigned long long*)idx, YwT_dummy, flag);
        direct_kernel<<<main_blocks, threads, 0, stream>>>(grid, pc, idx, Yw, Yb, Zw, Zb,
                                                           flag, 1, out, N);
    } else {
        // no workspace at all: assume int64 per the reference spec
        direct_kernel<<<main_blocks, threads, 0, stream>>>(grid, pc, idx, Yw, Yb, Zw, Zb,
                                                           nullptr, 1, out, N);
    }
}

// Round 2
// 90.255 us; speedup vs baseline: 1.8483x; 1.8483x over previous
//
#include <hip/hip_runtime.h>
#include <stdint.h>
#include <stddef.h>

#define NCELLS (512 * 512)   // 262144 grid cells
#define CG 64                // grid embedding channels
#define CPC 64               // point-cloud channels
#define CIN 128              // concat width
#define CH 32                // hidden width
#define COUT 3

// Workspace layout:
//   GZ4   : NCELLS float4  (4 MiB)  -- per-cell (W_emb@grid_col + b_eff), padded to 16B
//   Wpc4  : 64 float4      (1 KiB)  -- W_eff[:,64:128] as per-channel (t0,t1,t2,0)
//   Wemb4 : 64 float4      (1 KiB)  -- W_eff[:,0:64]  same layout
//   flag  : int                     -- grid_indices is int64?

// ---------------------------------------------------------------------------
// prep: fold the two linear layers into one.
//   W_eff[t][c] = sum_j Z_w[t][j] * Y_w[j][c]   (3 x 128)
//   b_eff[t]    = Z_b[t] + sum_j Z_w[t][j] * Y_b[j]
// Store per-channel float4 (t0,t1,t2, b-or-0). Also detect idx element width:
// if int64, every aligned 8-byte word is < 2^18 (indices < 262144); if int32,
// a u64 read combines two random indices -> >= 2^32 almost surely (8 probes).
// ---------------------------------------------------------------------------
__global__ void prep_kernel(const float* __restrict__ Yw,   // (32,128)
                            const float* __restrict__ Yb,   // (32,)
                            const float* __restrict__ Zw,   // (3,32)
                            const float* __restrict__ Zb,   // (3,)
                            const unsigned long long* __restrict__ idx_as_u64,
                            float4* __restrict__ Wemb4,     // [64]
                            float4* __restrict__ Wpc4,      // [64]
                            float4* __restrict__ beff,      // [1]
                            int* __restrict__ flag_is64) {
    int c = threadIdx.x;           // 0..127
    if (c < CIN) {
        float w0 = 0.f, w1 = 0.f, w2 = 0.f;
#pragma unroll
        for (int j = 0; j < CH; ++j) {
            float y = Yw[j * CIN + c];
            w0 = fmaf(Zw[0 * CH + j], y, w0);
            w1 = fmaf(Zw[1 * CH + j], y, w1);
            w2 = fmaf(Zw[2 * CH + j], y, w2);
        }
        float4 v = make_float4(w0, w1, w2, 0.f);
        if (c < CG) Wemb4[c] = v;
        else        Wpc4[c - CG] = v;
    }
    if (c == 0) {
        float b0 = Zb[0], b1 = Zb[1], b2 = Zb[2];
#pragma unroll
        for (int j = 0; j < CH; ++j) {
            float y = Yb[j];
            b0 = fmaf(Zw[0 * CH + j], y, b0);
            b1 = fmaf(Zw[1 * CH + j], y, b1);
            b2 = fmaf(Zw[2 * CH + j], y, b2);
        }
        *beff = make_float4(b0, b1, b2, 0.f);

        int is64 = 1;
        for (int i = 0; i < 8; ++i) {
            if (idx_as_u64[i] >= (unsigned long long)NCELLS) { is64 = 0; break; }
        }
        *flag_is64 = is64;
    }
}

// ---------------------------------------------------------------------------
// GZ table: GZ4[p] = W_emb @ grid[:, p] + b_eff.  4 cells per thread so the
// grid reads are float4 (16B/lane, fully coalesced); 64 MB in, 4 MB out.
// ---------------------------------------------------------------------------
__global__ void __launch_bounds__(256)
gz_kernel(const float* __restrict__ grid,     // (64, 262144)
          const float4* __restrict__ Wemb4,   // [64]
          const float4* __restrict__ beff,
          float4* __restrict__ GZ4) {
    int p0 = (blockIdx.x * blockDim.x + threadIdx.x) * 4;
    if (p0 >= NCELLS) return;

    float4 b = *beff;
    float a0x = b.x, a0y = b.y, a0z = b.z;
    float a1x = b.x, a1y = b.y, a1z = b.z;
    float a2x = b.x, a2y = b.y, a2z = b.z;
    float a3x = b.x, a3y = b.y, a3z = b.z;

#pragma unroll 8
    for (int c = 0; c < CG; ++c) {
        float4 g = *(const float4*)(grid + (size_t)c * NCELLS + p0);
        float4 w = Wemb4[c];   // wave-uniform -> scalar loads
        a0x = fmaf(w.x, g.x, a0x); a0y = fmaf(w.y, g.x, a0y); a0z = fmaf(w.z, g.x, a0z);
        a1x = fmaf(w.x, g.y, a1x); a1y = fmaf(w.y, g.y, a1y); a1z = fmaf(w.z, g.y, a1z);
        a2x = fmaf(w.x, g.z, a2x); a2y = fmaf(w.y, g.z, a2y); a2z = fmaf(w.z, g.z, a2z);
        a3x = fmaf(w.x, g.w, a3x); a3y = fmaf(w.y, g.w, a3y); a3z = fmaf(w.z, g.w, a3z);
    }

    GZ4[p0 + 0] = make_float4(a0x, a0y, a0z, 0.f);
    GZ4[p0 + 1] = make_float4(a1x, a1y, a1z, 0.f);
    GZ4[p0 + 2] = make_float4(a2x, a2y, a2z, 0.f);
    GZ4[p0 + 3] = make_float4(a3x, a3y, a3z, 0.f);
}

// ---------------------------------------------------------------------------
// Main: one thread per point.
//   out[i] = GZ4[idx[i]].xyz + W_pc @ pc[i]     (192 FMA, 16 float4 loads)
// GZ4 table is 4 MB -> per-XCD L2 resident after first touch.
// ---------------------------------------------------------------------------
__global__ void __launch_bounds__(256)
main_kernel(const float4* __restrict__ GZ4,
            const float* __restrict__ pc,       // (N,64)
            const void* __restrict__ idx_raw,
            const float4* __restrict__ Wpc4,    // [64]
            const int* __restrict__ flag_is64,
            float* __restrict__ out, int N) {
    int i = blockIdx.x * blockDim.x + threadIdx.x;
    if (i >= N) return;

    int is64 = *flag_is64;   // uniform
    int idx;
    if (is64) idx = (int)(((const long long*)idx_raw)[i]);
    else      idx = ((const int*)idx_raw)[i];

    float4 gz = GZ4[idx];
    float a0 = gz.x, a1 = gz.y, a2 = gz.z;

    const float4* pcp = (const float4*)(pc + (size_t)i * CPC);
#pragma unroll
    for (int q = 0; q < CPC / 4; ++q) {
        float4 x = pcp[q];
        float4 wA = Wpc4[4 * q + 0];
        float4 wB = Wpc4[4 * q + 1];
        float4 wC = Wpc4[4 * q + 2];
        float4 wD = Wpc4[4 * q + 3];
        a0 = fmaf(wA.x, x.x, a0); a1 = fmaf(wA.y, x.x, a1); a2 = fmaf(wA.z, x.x, a2);
        a0 = fmaf(wB.x, x.y, a0); a1 = fmaf(wB.y, x.y, a1); a2 = fmaf(wB.z, x.y, a2);
        a0 = fmaf(wC.x, x.z, a0); a1 = fmaf(wC.y, x.z, a1); a2 = fmaf(wC.z, x.z, a2);
        a0 = fmaf(wD.x, x.w, a0); a1 = fmaf(wD.y, x.w, a1); a2 = fmaf(wD.z, x.w, a2);
    }

    out[(size_t)i * COUT + 0] = a0;
    out[(size_t)i * COUT + 1] = a1;
    out[(size_t)i * COUT + 2] = a2;
}

// ---------------------------------------------------------------------------
// Fallback if workspace is too small (shouldn't happen: need is ~4.1 MB).
// Direct strided gather + fused weights computed inline per thread-block.
// ---------------------------------------------------------------------------
__global__ void __launch_bounds__(256)
direct_kernel(const float* __restrict__ grid,
              const float* __restrict__ pc,
              const void* __restrict__ idx_raw,
              const float* __restrict__ Yw, const float* __restrict__ Yb,
              const float* __restrict__ Zw, const float* __restrict__ Zb,
              float* __restrict__ out, int N) {
    int i = blockIdx.x * blockDim.x + threadIdx.x;
    if (i >= N) return;
    // assume int64 per reference spec on this path
    int idx = (int)(((const long long*)idx_raw)[i]);

    float h[CH];
#pragma unroll
    for (int j = 0; j < CH; ++j) h[j] = Yb[j];
    for (int c = 0; c < CG; ++c) {
        float g = grid[(size_t)c * NCELLS + idx];
#pragma unroll
        for (int j = 0; j < CH; ++j) h[j] = fmaf(Yw[j * CIN + c], g, h[j]);
    }
    const float4* pcp = (const float4*)(pc + (size_t)i * CPC);
#pragma unroll 2
    for (int c4 = 0; c4 < CPC / 4; ++c4) {
        float4 x = pcp[c4];
#pragma unroll
        for (int j = 0; j < CH; ++j) {
            const float* w = Yw + j * CIN + CG + c4 * 4;
            h[j] = fmaf(w[0], x.x, h[j]); h[j] = fmaf(w[1], x.y, h[j]);
            h[j] = fmaf(w[2], x.z, h[j]); h[j] = fmaf(w[3], x.w, h[j]);
        }
    }
#pragma unroll
    for (int t = 0; t < COUT; ++t) {
        float a = Zb[t];
#pragma unroll
        for (int j = 0; j < CH; ++j) a = fmaf(Zw[t * CH + j], h[j], a);
        out[(size_t)i * COUT + t] = a;
    }
}

extern "C" void kernel_launch(void* const* d_in, const int* in_sizes, int n_in,
                              void* d_out, int out_size, void* d_ws, size_t ws_size,
                              hipStream_t stream) {
    const float* grid = (const float*)d_in[0];   // (64,512,512)
    const float* pc   = (const float*)d_in[1];   // (N,64)
    const void*  idx  = d_in[2];                 // (N,) int64 (or int32, detected)
    const float* Yw   = (const float*)d_in[3];   // (32,128)
    const float* Yb   = (const float*)d_in[4];   // (32,)
    const float* Zw   = (const float*)d_in[5];   // (3,32)
    const float* Zb   = (const float*)d_in[6];   // (3,)
    float* out = (float*)d_out;
    const int N = in_sizes[2];

    const size_t GZ_bytes  = (size_t)NCELLS * sizeof(float4);   // 4 MiB
    const size_t W_bytes   = 64 * sizeof(float4);               // 1 KiB each
    const size_t need = GZ_bytes + 2 * W_bytes + sizeof(float4) + sizeof(int);

    const int threads = 256;
    const int main_blocks = (N + threads - 1) / threads;

    if (ws_size >= need) {
        char* w = (char*)d_ws;
        float4* GZ4   = (float4*)w;                       w += GZ_bytes;
        float4* Wemb4 = (float4*)w;                       w += W_bytes;
        float4* Wpc4  = (float4*)w;                       w += W_bytes;
        float4* beff  = (float4*)w;                       w += sizeof(float4);
        int*    flag  = (int*)w;

        prep_kernel<<<1, 128, 0, stream>>>(Yw, Yb, Zw, Zb,
                                           (const unsigned long long*)idx,
                                           Wemb4, Wpc4, beff, flag);
        gz_kernel<<<NCELLS / (threads * 4), threads, 0, stream>>>(grid, Wemb4, beff, GZ4);
        main_kernel<<<main_blocks, threads, 0, stream>>>(GZ4, pc, idx, Wpc4, flag, out, N);
    } else {
        direct_kernel<<<main_blocks, threads, 0, stream>>>(grid, pc, idx, Yw, Yb, Zw, Zb,
                                                           out, N);
    }
}

// Round 3
// 77.947 us; speedup vs baseline: 2.1402x; 1.1579x over previous
//
#include <hip/hip_runtime.h>
#include <stdint.h>
#include <stddef.h>

#define NCELLS (512 * 512)   // 262144 grid cells
#define CG 64                // grid embedding channels
#define CPC 64               // point-cloud channels
#define CIN 128              // concat width
#define CH 32                // hidden width
#define COUT 3

// Fused network: out = W_eff @ [emb; pc] + b_eff, W_eff = Z_w@Y_w (3x128).
// GZ4[p] = W_eff[:, :64] @ grid[:, p] + b_eff  (4 MiB table, cache-resident)
// main:   out[i] = GZ4[idx[i]].xyz + W_eff[:, 64:] @ pc[i]

// ---------------------------------------------------------------------------
// prep: fold the two linear layers; detect idx element width (int64 vs int32:
// aligned u64 reads of an int64 index array are < 2^18; of an int32 array
// they combine two random indices -> >= 2^32 almost surely; 8 probes).
// ---------------------------------------------------------------------------
__global__ void prep_kernel(const float* __restrict__ Yw,   // (32,128)
                            const float* __restrict__ Yb,   // (32,)
                            const float* __restrict__ Zw,   // (3,32)
                            const float* __restrict__ Zb,   // (3,)
                            const unsigned long long* __restrict__ idx_as_u64,
                            float4* __restrict__ Wemb4,     // [64]
                            float4* __restrict__ Wpc4,      // [64]
                            float4* __restrict__ beff,      // [1]
                            int* __restrict__ flag_is64) {
    int c = threadIdx.x;           // 0..127
    if (c < CIN) {
        float w0 = 0.f, w1 = 0.f, w2 = 0.f;
#pragma unroll
        for (int j = 0; j < CH; ++j) {
            float y = Yw[j * CIN + c];
            w0 = fmaf(Zw[0 * CH + j], y, w0);
            w1 = fmaf(Zw[1 * CH + j], y, w1);
            w2 = fmaf(Zw[2 * CH + j], y, w2);
        }
        float4 v = make_float4(w0, w1, w2, 0.f);
        if (c < CG) Wemb4[c] = v;
        else        Wpc4[c - CG] = v;
    }
    if (c == 0) {
        float b0 = Zb[0], b1 = Zb[1], b2 = Zb[2];
#pragma unroll
        for (int j = 0; j < CH; ++j) {
            float y = Yb[j];
            b0 = fmaf(Zw[0 * CH + j], y, b0);
            b1 = fmaf(Zw[1 * CH + j], y, b1);
            b2 = fmaf(Zw[2 * CH + j], y, b2);
        }
        *beff = make_float4(b0, b1, b2, 0.f);

        int is64 = 1;
        for (int i = 0; i < 8; ++i) {
            if (idx_as_u64[i] >= (unsigned long long)NCELLS) { is64 = 0; break; }
        }
        *flag_is64 = is64;
    }
}

// ---------------------------------------------------------------------------
// GZ table. 1 cell/thread -> 1024 blocks (4 waves/SIMD for latency hiding).
// Wave reads 256B contiguous per channel iteration; 64 MB in, 4 MB out.
// ---------------------------------------------------------------------------
__global__ void __launch_bounds__(256)
gz_kernel(const float* __restrict__ grid,     // (64, 262144)
          const float4* __restrict__ Wemb4,   // [64] (wave-uniform -> scalar)
          const float4* __restrict__ beff,
          float4* __restrict__ GZ4) {
    int p = blockIdx.x * blockDim.x + threadIdx.x;
    if (p >= NCELLS) return;

    float4 b = *beff;
    float a0 = b.x, a1 = b.y, a2 = b.z;

#pragma unroll 8
    for (int c = 0; c < CG; ++c) {
        float g = grid[(size_t)c * NCELLS + p];
        float4 w = Wemb4[c];
        a0 = fmaf(w.x, g, a0);
        a1 = fmaf(w.y, g, a1);
        a2 = fmaf(w.z, g, a2);
    }
    GZ4[p] = make_float4(a0, a1, a2, 0.f);
}

// ---------------------------------------------------------------------------
// Main: 8 lanes per point. Wave VMEM instr = 8 points x 128B contiguous
// half-rows -> 8 fully-consumed cache lines per instruction (ideal).
// Per-lane weights (channels ls*4..+3 and 32+ls*4..+3) hoisted out of the
// grid-stride loop. 3-level shfl_xor butterfly reduces the 8-lane group.
// ---------------------------------------------------------------------------
__global__ void __launch_bounds__(256)
main_kernel(const float4* __restrict__ GZ4,
            const float* __restrict__ pc,       // (N,64)
            const void* __restrict__ idx_raw,
            const float4* __restrict__ Wpc4,    // [64]
            const int* __restrict__ flag_is64,
            float* __restrict__ out, int N) {
    const int tid = blockIdx.x * blockDim.x + threadIdx.x;
    const int ls  = threadIdx.x & 7;            // lane-in-group
    const int gstride = (gridDim.x * blockDim.x) >> 3;
    const int is64 = *flag_is64;                // uniform

    // channels for this lane: x0 -> 4*ls+j ; x1 -> 32+4*ls+j
    const float4 wA0 = Wpc4[4 * ls + 0];
    const float4 wA1 = Wpc4[4 * ls + 1];
    const float4 wA2 = Wpc4[4 * ls + 2];
    const float4 wA3 = Wpc4[4 * ls + 3];
    const float4 wB0 = Wpc4[32 + 4 * ls + 0];
    const float4 wB1 = Wpc4[32 + 4 * ls + 1];
    const float4 wB2 = Wpc4[32 + 4 * ls + 2];
    const float4 wB3 = Wpc4[32 + 4 * ls + 3];

    for (int p = tid >> 3; p < N; p += gstride) {
        const float4* pcp = (const float4*)(pc + (size_t)p * CPC);
        float4 x0 = pcp[ls];
        float4 x1 = pcp[8 + ls];

        float a0, a1, a2;
        a0 = wA0.x * x0.x;            a1 = wA0.y * x0.x;            a2 = wA0.z * x0.x;
        a0 = fmaf(wA1.x, x0.y, a0);   a1 = fmaf(wA1.y, x0.y, a1);   a2 = fmaf(wA1.z, x0.y, a2);
        a0 = fmaf(wA2.x, x0.z, a0);   a1 = fmaf(wA2.y, x0.z, a1);   a2 = fmaf(wA2.z, x0.z, a2);
        a0 = fmaf(wA3.x, x0.w, a0);   a1 = fmaf(wA3.y, x0.w, a1);   a2 = fmaf(wA3.z, x0.w, a2);
        a0 = fmaf(wB0.x, x1.x, a0);   a1 = fmaf(wB0.y, x1.x, a1);   a2 = fmaf(wB0.z, x1.x, a2);
        a0 = fmaf(wB1.x, x1.y, a0);   a1 = fmaf(wB1.y, x1.y, a1);   a2 = fmaf(wB1.z, x1.y, a2);
        a0 = fmaf(wB2.x, x1.z, a0);   a1 = fmaf(wB2.y, x1.z, a1);   a2 = fmaf(wB2.z, x1.z, a2);
        a0 = fmaf(wB3.x, x1.w, a0);   a1 = fmaf(wB3.y, x1.w, a1);   a2 = fmaf(wB3.z, x1.w, a2);

#pragma unroll
        for (int m = 1; m < 8; m <<= 1) {
            a0 += __shfl_xor(a0, m, 8);
            a1 += __shfl_xor(a1, m, 8);
            a2 += __shfl_xor(a2, m, 8);
        }

        if (ls == 0) {
            int idx;
            if (is64) idx = (int)(((const long long*)idx_raw)[p]);
            else      idx = ((const int*)idx_raw)[p];
            float4 gz = GZ4[idx];
            out[(size_t)p * COUT + 0] = a0 + gz.x;
            out[(size_t)p * COUT + 1] = a1 + gz.y;
            out[(size_t)p * COUT + 2] = a2 + gz.z;
        }
    }
}

// ---------------------------------------------------------------------------
// Fallback if workspace is too small (need ~4.1 MB). Direct strided gather.
// ---------------------------------------------------------------------------
__global__ void __launch_bounds__(256)
direct_kernel(const float* __restrict__ grid,
              const float* __restrict__ pc,
              const void* __restrict__ idx_raw,
              const float* __restrict__ Yw, const float* __restrict__ Yb,
              const float* __restrict__ Zw, const float* __restrict__ Zb,
              float* __restrict__ out, int N) {
    int i = blockIdx.x * blockDim.x + threadIdx.x;
    if (i >= N) return;
    int idx = (int)(((const long long*)idx_raw)[i]);   // reference spec: int64

    float h[CH];
#pragma unroll
    for (int j = 0; j < CH; ++j) h[j] = Yb[j];
    for (int c = 0; c < CG; ++c) {
        float g = grid[(size_t)c * NCELLS + idx];
#pragma unroll
        for (int j = 0; j < CH; ++j) h[j] = fmaf(Yw[j * CIN + c], g, h[j]);
    }
    const float4* pcp = (const float4*)(pc + (size_t)i * CPC);
#pragma unroll 2
    for (int c4 = 0; c4 < CPC / 4; ++c4) {
        float4 x = pcp[c4];
#pragma unroll
        for (int j = 0; j < CH; ++j) {
            const float* w = Yw + j * CIN + CG + c4 * 4;
            h[j] = fmaf(w[0], x.x, h[j]); h[j] = fmaf(w[1], x.y, h[j]);
            h[j] = fmaf(w[2], x.z, h[j]); h[j] = fmaf(w[3], x.w, h[j]);
        }
    }
#pragma unroll
    for (int t = 0; t < COUT; ++t) {
        float a = Zb[t];
#pragma unroll
        for (int j = 0; j < CH; ++j) a = fmaf(Zw[t * CH + j], h[j], a);
        out[(size_t)i * COUT + t] = a;
    }
}

extern "C" void kernel_launch(void* const* d_in, const int* in_sizes, int n_in,
                              void* d_out, int out_size, void* d_ws, size_t ws_size,
                              hipStream_t stream) {
    const float* grid = (const float*)d_in[0];   // (64,512,512)
    const float* pc   = (const float*)d_in[1];   // (N,64)
    const void*  idx  = d_in[2];                 // (N,) int64 (or int32, detected)
    const float* Yw   = (const float*)d_in[3];   // (32,128)
    const float* Yb   = (const float*)d_in[4];   // (32,)
    const float* Zw   = (const float*)d_in[5];   // (3,32)
    const float* Zb   = (const float*)d_in[6];   // (3,)
    float* out = (float*)d_out;
    const int N = in_sizes[2];

    const size_t GZ_bytes = (size_t)NCELLS * sizeof(float4);   // 4 MiB
    const size_t W_bytes  = 64 * sizeof(float4);               // 1 KiB each
    const size_t need = GZ_bytes + 2 * W_bytes + sizeof(float4) + sizeof(int);

    if (ws_size >= need) {
        char* w = (char*)d_ws;
        float4* GZ4   = (float4*)w;                       w += GZ_bytes;
        float4* Wemb4 = (float4*)w;                       w += W_bytes;
        float4* Wpc4  = (float4*)w;                       w += W_bytes;
        float4* beff  = (float4*)w;                       w += sizeof(float4);
        int*    flag  = (int*)w;

        prep_kernel<<<1, 128, 0, stream>>>(Yw, Yb, Zw, Zb,
                                           (const unsigned long long*)idx,
                                           Wemb4, Wpc4, beff, flag);
        gz_kernel<<<NCELLS / 256, 256, 0, stream>>>(grid, Wemb4, beff, GZ4);
        // 8 lanes/point, grid-stride; 4096 blocks = 16/CU queued, 8 resident
        main_kernel<<<4096, 256, 0, stream>>>(GZ4, pc, idx, Wpc4, flag, out, N);
    } else {
        const int threads = 256;
        direct_kernel<<<(N + threads - 1) / threads, threads, 0, stream>>>(
            grid, pc, idx, Yw, Yb, Zw, Zb, out, N);
    }
}